// Round 1
// baseline (1645.868 us; speedup 1.0000x reference)
//
#include <hip/hip_runtime.h>
#include <hip/hip_bf16.h>

// ============================================================================
// ConvTemporalGraphical — round 1: correct register-tiled VALU baseline.
//
// Pipeline (all intermediates bf16 in d_ws):
//   k1_conv80 : x2=unfold3(x) gathered on the fly; one fused 1x1 conv producing
//               80 channels = [a1(16) | xd(16) | x1(48)] (+bias).
//               Writes a1buf [n][16][t][80pad] and hxT [n][t][g][w1][c]
//               (g=0..2: x1 k-groups, g=3: xd) — c-contiguous for k3.
//   k2a/k2b   : S[n][w1][w2] = sum_{o,t} a1*a1 via fp32 atomics, then /75 and
//               column softmax (over w1) -> att [n][75][75] fp32.
//   k3_graph  : sum12[c][w] = sum_{g,w1} hx[g][c][w1] * B[g][w1][w] with
//               B = [Aeff(0..2) | att] staged bf16 in LDS (K=300 contraction).
//               conv_d commutes with att (softmax cols sum to 1), saving 2.4x.
//   k4_out    : conv3d (1,3,1) over (c,ww) + bias + BN + residual + relu.
//
// ws layout (bytes): a1buf 41,943,040 | hxT 157,286,400 | sum12 41,943,040 |
//                    attS 720,000 | att 720,000  => total 242,612,480.
// ============================================================================

typedef unsigned short u16;
typedef unsigned int   u32;

__device__ __forceinline__ float b2f(u32 u) {
    union { u32 i; float f; } x; x.i = (u & 0xffffu) << 16; return x.f;
}
__device__ __forceinline__ u16 f2b(float f) {
    union { float f; u32 i; } x; x.f = f;
    u32 i = x.i;
    return (u16)((i + 0x7fffu + ((i >> 16) & 1u)) >> 16);   // RNE
}
__device__ __forceinline__ u32 pack2(float a, float b) {
    return (u32)f2b(a) | ((u32)f2b(b) << 16);
}
__device__ __forceinline__ void unpack8(uint4 u, float* f) {
    f[0] = b2f(u.x); f[1] = b2f(u.x >> 16);
    f[2] = b2f(u.y); f[3] = b2f(u.y >> 16);
    f[4] = b2f(u.z); f[5] = b2f(u.z >> 16);
    f[6] = b2f(u.w); f[7] = b2f(u.w >> 16);
}
__device__ __forceinline__ void unpack4(uint2 u, float* f) {
    f[0] = b2f(u.x); f[1] = b2f(u.x >> 16);
    f[2] = b2f(u.y); f[3] = b2f(u.y >> 16);
}

// ---------------------------------------------------------------------------
// k1: fused 80-channel 1x1 conv over gathered x2. Block = 2 t's of one n.
// 8o x 8w register tiles (200 active threads), bf16 LDS operands.
// ---------------------------------------------------------------------------
__global__ __launch_bounds__(256) void k1_conv80(
    const float* __restrict__ x,
    const float* __restrict__ wa, const float* __restrict__ ba,
    const float* __restrict__ wd, const float* __restrict__ bd,
    const float* __restrict__ wc, const float* __restrict__ bc,
    u16* __restrict__ a1buf, u16* __restrict__ hxT)
{
    __shared__ u16 Wl[64 * 80];        // [c][o] transposed weights, bf16
    __shared__ u16 xsh[2 * 64 * 80];   // [ts][c][w(pad80)]
    const int b   = blockIdx.x;
    const int n   = b >> 8;
    const int t0  = (b & 255) << 1;
    const int tid = threadIdx.x;

    for (int e = tid; e < 64 * 80; e += 256) {
        int c = e / 80, o = e - c * 80;
        float v;
        if (o < 16)      v = wa[o * 64 + c];
        else if (o < 32) v = wd[(o - 16) * 64 + c];
        else             v = wc[(o - 32) * 64 + c];
        Wl[c * 80 + o] = f2b(v);
    }
    for (int e = tid; e < 2 * 64 * 80; e += 256) {
        int ts = e / 5120, r = e - ts * 5120;
        int c = r / 80, w = r - c * 80;
        float v = 0.f;
        if (w < 75) {
            int i = w / 25, vv = w - i * 25;
            int tt = t0 + ts + i - 1;                    // unfold3, zero-pad T
            if (tt >= 0 && tt < 512)
                v = x[(((size_t)n * 64 + c) * 512 + tt) * 25 + vv];
        }
        xsh[e] = f2b(v);                                 // e == (ts*64+c)*80+w
    }
    __syncthreads();

    if (tid < 200) {
        const int ts   = tid / 100;
        const int tile = tid - ts * 100;
        const int o0   = (tile / 10) * 8;
        const int w0   = (tile % 10) * 8;
        const int t    = t0 + ts;

        float acc[8][8];
        #pragma unroll
        for (int i = 0; i < 8; ++i)
            #pragma unroll
            for (int j = 0; j < 8; ++j) acc[i][j] = 0.f;

        #pragma unroll 4
        for (int c = 0; c < 64; ++c) {
            float wf[8], xf[8];
            unpack8(*(const uint4*)&Wl[c * 80 + o0], wf);
            unpack8(*(const uint4*)&xsh[(ts * 64 + c) * 80 + w0], xf);
            #pragma unroll
            for (int i = 0; i < 8; ++i)
                #pragma unroll
                for (int j = 0; j < 8; ++j)
                    acc[i][j] = fmaf(wf[i], xf[j], acc[i][j]);
        }

        if (o0 < 16) {   // a1 path: per-o rows, w-contiguous
            #pragma unroll
            for (int i = 0; i < 8; ++i) {
                const int o = o0 + i;
                const float bias = ba[o];
                size_t base = (((size_t)n * 16 + o) * 512 + t) * 80 + w0;
                if (w0 < 72) {
                    uint4 s;
                    s.x = pack2(acc[i][0] + bias, acc[i][1] + bias);
                    s.y = pack2(acc[i][2] + bias, acc[i][3] + bias);
                    s.z = pack2(acc[i][4] + bias, acc[i][5] + bias);
                    s.w = pack2(acc[i][6] + bias, acc[i][7] + bias);
                    *(uint4*)&a1buf[base] = s;
                } else {                                  // w = 72..74 only
                    a1buf[base + 0] = f2b(acc[i][0] + bias);
                    a1buf[base + 1] = f2b(acc[i][1] + bias);
                    a1buf[base + 2] = f2b(acc[i][2] + bias);
                }
            }
        } else {         // hxT path: per-w rows, c-contiguous (8 c's = 16B)
            int g, c0;
            if (o0 < 32) { g = 3; c0 = o0 - 16; }
            else         { g = (o0 - 32) >> 4; c0 = (o0 - 32) & 15; }
            float bias[8];
            #pragma unroll
            for (int i = 0; i < 8; ++i) {
                int o = o0 + i;
                bias[i] = (o < 32) ? bd[o - 16] : bc[o - 32];
            }
            const int wlim = (w0 < 72) ? 8 : 3;
            for (int j = 0; j < wlim; ++j) {
                const int w = w0 + j;
                uint4 s;
                s.x = pack2(acc[0][j] + bias[0], acc[1][j] + bias[1]);
                s.y = pack2(acc[2][j] + bias[2], acc[3][j] + bias[3]);
                s.z = pack2(acc[4][j] + bias[4], acc[5][j] + bias[5]);
                s.w = pack2(acc[6][j] + bias[6], acc[7][j] + bias[7]);
                size_t base = ((((size_t)n * 512 + t) * 4 + g) * 75 + w) * 16 + c0;
                *(uint4*)&hxT[base] = s;
            }
        }
    }
}

// ---------------------------------------------------------------------------
// k2a: partial S[n][w1][w2] += sum over (o, 256 t's) a1*a1, fp32 atomics.
// Block = (n, o, t-half). 4x4 register tiles over a padded 76-col row cache.
// ---------------------------------------------------------------------------
__global__ __launch_bounds__(256) void k2a_scores(
    const u16* __restrict__ a1buf, float* __restrict__ attS)
{
    __shared__ float ch[64 * 76];
    const int b   = blockIdx.x;
    const int n   = b >> 5;
    const int o   = (b & 31) >> 1;
    const int th  = b & 1;
    const int tid = threadIdx.x;

    const bool two = (tid < 105);                 // tiles 256..360
    const int w1a = (tid / 19) * 4, w2a = (tid % 19) * 4;
    const int w1b = ((tid + 256) / 19) * 4, w2b = ((tid + 256) % 19) * 4;

    float acc1[16], acc2[16];
    #pragma unroll
    for (int i = 0; i < 16; ++i) { acc1[i] = 0.f; acc2[i] = 0.f; }

    for (int ch0 = 0; ch0 < 4; ++ch0) {
        __syncthreads();
        const int tb = th * 256 + ch0 * 64;
        for (int e = tid; e < 64 * 76; e += 256) {
            int tt = e / 76, w = e - tt * 76;
            float v = 0.f;
            if (w < 75)
                v = b2f(a1buf[(((size_t)n * 16 + o) * 512 + tb + tt) * 80 + w]);
            ch[e] = v;                            // pad col 75 = 0
        }
        __syncthreads();
        for (int r = 0; r < 64; ++r) {
            const float* row = &ch[r * 76];
            float4 p = *(const float4*)&row[w1a];
            float4 q = *(const float4*)&row[w2a];
            float pa[4] = {p.x, p.y, p.z, p.w}, qa[4] = {q.x, q.y, q.z, q.w};
            #pragma unroll
            for (int i = 0; i < 4; ++i)
                #pragma unroll
                for (int j = 0; j < 4; ++j)
                    acc1[i * 4 + j] = fmaf(pa[i], qa[j], acc1[i * 4 + j]);
            if (two) {
                float4 p2 = *(const float4*)&row[w1b];
                float4 q2 = *(const float4*)&row[w2b];
                float pb[4] = {p2.x, p2.y, p2.z, p2.w}, qb[4] = {q2.x, q2.y, q2.z, q2.w};
                #pragma unroll
                for (int i = 0; i < 4; ++i)
                    #pragma unroll
                    for (int j = 0; j < 4; ++j)
                        acc2[i * 4 + j] = fmaf(pb[i], qb[j], acc2[i * 4 + j]);
            }
        }
    }

    #pragma unroll
    for (int i = 0; i < 4; ++i)
        #pragma unroll
        for (int j = 0; j < 4; ++j) {
            int w1 = w1a + i, w2 = w2a + j;
            if (w1 < 75 && w2 < 75)
                atomicAdd(&attS[(size_t)n * 5625 + w1 * 75 + w2], acc1[i * 4 + j]);
        }
    if (two) {
        #pragma unroll
        for (int i = 0; i < 4; ++i)
            #pragma unroll
            for (int j = 0; j < 4; ++j) {
                int w1 = w1b + i, w2 = w2b + j;
                if (w1 < 75 && w2 < 75)
                    atomicAdd(&attS[(size_t)n * 5625 + w1 * 75 + w2], acc2[i * 4 + j]);
            }
    }
}

// ---------------------------------------------------------------------------
// k2b: scale by 1/75 and softmax over w1 (dim -2) per column w2.
// ---------------------------------------------------------------------------
__global__ __launch_bounds__(256) void k2b_softmax(
    const float* __restrict__ attS, float* __restrict__ att)
{
    __shared__ float S[5625];
    const int n = blockIdx.x, tid = threadIdx.x;
    for (int e = tid; e < 5625; e += 256)
        S[e] = attS[(size_t)n * 5625 + e] * (1.0f / 75.0f);
    __syncthreads();
    if (tid < 75) {
        const int w2 = tid;
        float m = -1e30f;
        for (int w1 = 0; w1 < 75; ++w1) m = fmaxf(m, S[w1 * 75 + w2]);
        float s = 0.f;
        for (int w1 = 0; w1 < 75; ++w1) {
            float e = __expf(S[w1 * 75 + w2] - m);
            S[w1 * 75 + w2] = e;                  // own column: no race
            s += e;
        }
        const float r = 1.0f / s;
        for (int w1 = 0; w1 < 75; ++w1)
            att[(size_t)n * 5625 + w1 * 75 + w2] = S[w1 * 75 + w2] * r;
    }
}

// ---------------------------------------------------------------------------
// k3: K=300 contraction. B = [Aeff(3x75) | att] bf16 in LDS (48KB).
// A-operand (hxT) read straight from global: the 10 w-tiles of a wave hit the
// same address -> merged request; each element fetched ~once overall.
// Block = (n, 8 t's), 4c x 8w register tiles, 320 tiles.
// ---------------------------------------------------------------------------
__global__ __launch_bounds__(256) void k3_graph(
    const u16* __restrict__ hxT,
    const float* __restrict__ A, const float* __restrict__ PA,
    const float* __restrict__ att,
    u16* __restrict__ sum12)
{
    __shared__ u16 Bs[300 * 80];
    const int b   = blockIdx.x;
    const int n   = b >> 6;
    const int t0  = (b & 63) << 3;
    const int tid = threadIdx.x;

    for (int e = tid; e < 300 * 80; e += 256) {
        int k = e / 80, w = e - k * 80;
        float v = 0.f;
        if (w < 75) {
            int g = k / 75, w1 = k - g * 75;
            if (g < 3) { int idx = (g * 75 + w1) * 75 + w; v = A[idx] + PA[idx]; }
            else       v = att[(size_t)n * 5625 + w1 * 75 + w];
        }
        Bs[e] = f2b(v);                           // w>=75 pad = 0
    }
    __syncthreads();

    for (int tile = tid; tile < 320; tile += 256) {
        const int ts = tile / 40;
        const int r  = tile - ts * 40;
        const int c0 = (r / 10) * 4;
        const int w0 = (r % 10) * 8;
        const int t  = t0 + ts;
        const u16* hxp = hxT + ((size_t)n * 512 + t) * 4800 + c0;  // + k*16

        float acc[4][8];
        #pragma unroll
        for (int i = 0; i < 4; ++i)
            #pragma unroll
            for (int j = 0; j < 8; ++j) acc[i][j] = 0.f;

        #pragma unroll 4
        for (int k = 0; k < 300; ++k) {
            float af[4], bf[8];
            unpack4(*(const uint2*)(hxp + (size_t)k * 16), af);
            unpack8(*(const uint4*)&Bs[k * 80 + w0], bf);
            #pragma unroll
            for (int i = 0; i < 4; ++i)
                #pragma unroll
                for (int j = 0; j < 8; ++j)
                    acc[i][j] = fmaf(af[i], bf[j], acc[i][j]);
        }

        #pragma unroll
        for (int i = 0; i < 4; ++i) {
            uint4 s;
            s.x = pack2(acc[i][0], acc[i][1]);
            s.y = pack2(acc[i][2], acc[i][3]);
            s.z = pack2(acc[i][4], acc[i][5]);
            s.w = pack2(acc[i][6], acc[i][7]);
            size_t base = (((size_t)n * 512 + t) * 16 + c0 + i) * 80 + w0;
            *(uint4*)&sum12[base] = s;
        }
    }
}

// ---------------------------------------------------------------------------
// k4: conv3d(1,3,1) + out bias + BN(inference) + residual + relu.
// Block = (n, 4 t's); thread = (o, ts); out_w row cached in 48 registers.
// ss padded [ww][28] so the v-dim reads are aligned float4.
// ---------------------------------------------------------------------------
__global__ __launch_bounds__(256) void k4_out(
    const u16* __restrict__ sum12,
    const float* __restrict__ ow, const float* __restrict__ obias,
    const float* __restrict__ bg, const float* __restrict__ bb,
    const float* __restrict__ bm, const float* __restrict__ bv,
    const float* __restrict__ x, float* __restrict__ out)
{
    __shared__ float ss[4][16][3][28];
    const int b   = blockIdx.x;
    const int n   = b >> 7;
    const int t0  = (b & 127) << 2;
    const int tid = threadIdx.x;
    const int o   = tid & 63;
    const int ts  = tid >> 6;

    float* sf = &ss[0][0][0][0];
    for (int e = tid; e < 4 * 16 * 3 * 28; e += 256) sf[e] = 0.f;
    __syncthreads();
    for (int e = tid; e < 4 * 16 * 75; e += 256) {
        int ts2 = e / 1200, r = e - ts2 * 1200;
        int c = r / 75, w = r - c * 75;
        int ww = w / 25, v = w - ww * 25;
        ss[ts2][c][ww][v] =
            b2f(sum12[(((size_t)n * 512 + t0 + ts2) * 16 + c) * 80 + w]);
    }
    __syncthreads();

    float wreg[48];
    #pragma unroll
    for (int k = 0; k < 48; ++k) wreg[k] = ow[o * 48 + k];
    const float scale = bg[o] * rsqrtf(bv[o] + 1e-5f);
    const float shift = bb[o] - bm[o] * scale;
    const float obv   = obias[o];

    float accs[25];
    #pragma unroll
    for (int v = 0; v < 25; ++v) accs[v] = 0.f;

    for (int c = 0; c < 16; ++c) {
        #pragma unroll
        for (int ww = 0; ww < 3; ++ww) {
            const float wv = wreg[c * 3 + ww];
            const float* sp = &ss[ts][c][ww][0];
            #pragma unroll
            for (int j = 0; j < 6; ++j) {
                float4 s4 = *(const float4*)&sp[j * 4];
                accs[j * 4 + 0] = fmaf(wv, s4.x, accs[j * 4 + 0]);
                accs[j * 4 + 1] = fmaf(wv, s4.y, accs[j * 4 + 1]);
                accs[j * 4 + 2] = fmaf(wv, s4.z, accs[j * 4 + 2]);
                accs[j * 4 + 3] = fmaf(wv, s4.w, accs[j * 4 + 3]);
            }
            accs[24] = fmaf(wv, sp[24], accs[24]);
        }
    }

    const int t = t0 + ts;
    const size_t base = (((size_t)n * 64 + o) * 512 + t) * 25;
    #pragma unroll
    for (int v = 0; v < 25; ++v) {
        float y = (accs[v] + obv) * scale + shift + x[base + v];
        out[base + v] = fmaxf(y, 0.f);
    }
}

// ---------------------------------------------------------------------------
extern "C" void kernel_launch(void* const* d_in, const int* in_sizes, int n_in,
                              void* d_out, int out_size, void* d_ws, size_t ws_size,
                              hipStream_t stream)
{
    const float* x  = (const float*)d_in[0];
    const float* A  = (const float*)d_in[1];
    const float* PA = (const float*)d_in[2];
    const float* wa = (const float*)d_in[3];
    const float* ba = (const float*)d_in[4];
    const float* wd = (const float*)d_in[5];
    const float* bd = (const float*)d_in[6];
    const float* wc = (const float*)d_in[7];
    const float* bc = (const float*)d_in[8];
    const float* ow = (const float*)d_in[9];
    const float* ob = (const float*)d_in[10];
    const float* bg = (const float*)d_in[11];
    const float* bb = (const float*)d_in[12];
    const float* bm = (const float*)d_in[13];
    const float* bv = (const float*)d_in[14];
    float* out = (float*)d_out;

    char* ws = (char*)d_ws;
    u16*   a1buf = (u16*)(ws);                                   // 41,943,040 B
    u16*   hxT   = (u16*)(ws + 41943040);                        // 157,286,400 B
    u16*   sum12 = (u16*)(ws + 41943040 + 157286400);            // 41,943,040 B
    float* attS  = (float*)(ws + 241172480);                     // 720,000 B
    float* att   = (float*)(ws + 241892480);                     // 720,000 B

    hipMemsetAsync(attS, 0, 32 * 5625 * 4, stream);              // zero before atomics

    k1_conv80 <<<8192, 256, 0, stream>>>(x, wa, ba, wd, bd, wc, bc, a1buf, hxT);
    k2a_scores<<<1024, 256, 0, stream>>>(a1buf, attS);
    k2b_softmax<<<32,  256, 0, stream>>>(attS, att);
    k3_graph  <<<2048, 256, 0, stream>>>(hxT, A, PA, att, sum12);
    k4_out    <<<4096, 256, 0, stream>>>(sum12, ow, ob, bg, bb, bm, bv, x, out);
}

// Round 2
// 926.216 us; speedup vs baseline: 1.7770x; 1.7770x over previous
//
#include <hip/hip_runtime.h>
#include <hip/hip_bf16.h>

// ============================================================================
// ConvTemporalGraphical — round 2: conv-before-unfold restructure.
//
// Key algebra: 1x1 convs commute with UnfoldTemporalWindows, and conv_d
// commutes with the att matmul (softmax cols sum to 1). So:
//   k1: hc = fused 80-ch 1x1 conv on x directly (N,80,T,V) — 3x fewer FLOPs
//       and writes than conv-on-unfolded. Two output layouts:
//         a1c [n][16][512][25]        (conv_a out, for k2a)
//         hcp [n][512*25][64]         (ch-contiguous: 0..15=xd, 16..63=x1 g)
//   k2a/k2b: attention scores with unfold-on-read + column softmax.
//   k3: sum12[n][t][16c][80w] = sum_{g,w1} hx[g][c][t][w1] * B[g][w1][w],
//       B=[Aeff|att] bf16 LDS (48KB), hx staged via trivially-coalesced uint4
//       copy of hcp rows (32KB) with t-shift unfold. 320 thr, 1 tile each.
//   k4: conv3d(1,3,1) + bias + BN + residual + relu.
//
// ws: a1c 13,107,200 | hcp 52,428,800 | sum12 41,943,040 | attS 720,000 |
//     att 720,000  => 108,919,040 B.
// ============================================================================

typedef unsigned short u16;
typedef unsigned int   u32;

__device__ __forceinline__ float b2f(u32 u) {
    union { u32 i; float f; } x; x.i = (u & 0xffffu) << 16; return x.f;
}
__device__ __forceinline__ u16 f2b(float f) {
    union { float f; u32 i; } x; x.f = f;
    u32 i = x.i;
    return (u16)((i + 0x7fffu + ((i >> 16) & 1u)) >> 16);   // RNE
}
__device__ __forceinline__ u32 pack2(float a, float b) {
    return (u32)f2b(a) | ((u32)f2b(b) << 16);
}
__device__ __forceinline__ void unpack8(uint4 u, float* f) {
    f[0] = b2f(u.x); f[1] = b2f(u.x >> 16);
    f[2] = b2f(u.y); f[3] = b2f(u.y >> 16);
    f[4] = b2f(u.z); f[5] = b2f(u.z >> 16);
    f[6] = b2f(u.w); f[7] = b2f(u.w >> 16);
}
__device__ __forceinline__ void unpack4(uint2 u, float* f) {
    f[0] = b2f(u.x); f[1] = b2f(u.x >> 16);
    f[2] = b2f(u.y); f[3] = b2f(u.y >> 16);
}

// ---------------------------------------------------------------------------
// k1: 80-ch 1x1 conv on x directly. Block = (n, 16 t's). 250 threads compute
// 8ch x 16(t*v) register tiles over K=64; LDS operands bf16.
// ---------------------------------------------------------------------------
__global__ __launch_bounds__(256, 2) void k1_conv80(
    const float* __restrict__ x,
    const float* __restrict__ wa, const float* __restrict__ ba,
    const float* __restrict__ wd, const float* __restrict__ bd,
    const float* __restrict__ wc, const float* __restrict__ bc,
    u16* __restrict__ a1c, u16* __restrict__ hcp)
{
    __shared__ u16 Wl[64 * 80];     // [c][o]
    __shared__ u16 xsh[64 * 400];   // [c][t*25+v], t local 0..15
    const int b   = blockIdx.x;
    const int n   = b >> 5;
    const int t0  = (b & 31) << 4;
    const int tid = threadIdx.x;

    for (int e = tid; e < 64 * 80; e += 256) {
        int c = e / 80, o = e - c * 80;
        float v;
        if (o < 16)      v = wa[o * 64 + c];
        else if (o < 32) v = wd[(o - 16) * 64 + c];
        else             v = wc[(o - 32) * 64 + c];
        Wl[e] = f2b(v);
    }
    for (int idx = tid; idx < 6400; idx += 256) {       // 100 float4 per c
        int c = idx / 100, r4 = idx - c * 100;
        const float4 v = *(const float4*)&x[(((size_t)n * 64 + c) * 512 + t0) * 25 + r4 * 4];
        *(u32*)&xsh[c * 400 + r4 * 4]     = pack2(v.x, v.y);
        *(u32*)&xsh[c * 400 + r4 * 4 + 2] = pack2(v.z, v.w);
    }
    __syncthreads();

    if (tid < 250) {
        const int ch0 = (tid / 25) * 8;
        const int n0  = (tid % 25) * 16;

        float acc[8][16];
        #pragma unroll
        for (int i = 0; i < 8; ++i)
            #pragma unroll
            for (int j = 0; j < 16; ++j) acc[i][j] = 0.f;

        #pragma unroll 4
        for (int c = 0; c < 64; ++c) {
            float wf[8], xf[16];
            unpack8(*(const uint4*)&Wl[c * 80 + ch0], wf);
            unpack8(*(const uint4*)&xsh[c * 400 + n0], xf);
            unpack8(*(const uint4*)&xsh[c * 400 + n0 + 8], xf + 8);
            #pragma unroll
            for (int i = 0; i < 8; ++i)
                #pragma unroll
                for (int j = 0; j < 16; ++j)
                    acc[i][j] = fmaf(wf[i], xf[j], acc[i][j]);
        }

        if (ch0 < 16) {   // a1c: [n][o][512*25], tv-contiguous
            #pragma unroll
            for (int i = 0; i < 8; ++i) {
                const int o = ch0 + i;
                const float bias = ba[o];
                size_t base = ((size_t)n * 16 + o) * 12800 + t0 * 25 + n0;
                uint4 s0, s1;
                s0.x = pack2(acc[i][0] + bias,  acc[i][1] + bias);
                s0.y = pack2(acc[i][2] + bias,  acc[i][3] + bias);
                s0.z = pack2(acc[i][4] + bias,  acc[i][5] + bias);
                s0.w = pack2(acc[i][6] + bias,  acc[i][7] + bias);
                s1.x = pack2(acc[i][8] + bias,  acc[i][9] + bias);
                s1.y = pack2(acc[i][10] + bias, acc[i][11] + bias);
                s1.z = pack2(acc[i][12] + bias, acc[i][13] + bias);
                s1.w = pack2(acc[i][14] + bias, acc[i][15] + bias);
                *(uint4*)&a1c[base]     = s0;
                *(uint4*)&a1c[base + 8] = s1;
            }
        } else {          // hcp: [n][tv][64], ch-contiguous (8 ch = 16B)
            const int cc = ch0 - 16;
            float bias[8];
            #pragma unroll
            for (int i = 0; i < 8; ++i) {
                int ch = ch0 + i;
                bias[i] = (ch < 32) ? bd[ch - 16] : bc[ch - 32];
            }
            #pragma unroll
            for (int j = 0; j < 16; ++j) {
                uint4 s;
                s.x = pack2(acc[0][j] + bias[0], acc[1][j] + bias[1]);
                s.y = pack2(acc[2][j] + bias[2], acc[3][j] + bias[3]);
                s.z = pack2(acc[4][j] + bias[4], acc[5][j] + bias[5]);
                s.w = pack2(acc[6][j] + bias[6], acc[7][j] + bias[7]);
                *(uint4*)&hcp[((size_t)n * 12800 + t0 * 25 + n0 + j) * 64 + cc] = s;
            }
        }
    }
}

// ---------------------------------------------------------------------------
// k2a: S[n][w1][w2] += sum_{o, 256 t's} a1[w1]*a1[w2], unfold-on-read,
// fp32 atomics. Block = (n, o, t-half).
// ---------------------------------------------------------------------------
__global__ __launch_bounds__(256) void k2a_scores(
    const u16* __restrict__ a1c, float* __restrict__ attS)
{
    __shared__ float ch[64 * 76];
    const int b   = blockIdx.x;
    const int n   = b >> 5;
    const int o   = (b & 31) >> 1;
    const int th  = b & 1;
    const int tid = threadIdx.x;

    const bool two = (tid < 105);
    const int w1a = (tid / 19) * 4, w2a = (tid % 19) * 4;
    const int w1b = ((tid + 256) / 19) * 4, w2b = ((tid + 256) % 19) * 4;

    float acc1[16], acc2[16];
    #pragma unroll
    for (int i = 0; i < 16; ++i) { acc1[i] = 0.f; acc2[i] = 0.f; }

    for (int ch0 = 0; ch0 < 4; ++ch0) {
        __syncthreads();
        const int tb = th * 256 + ch0 * 64;
        for (int e = tid; e < 64 * 76; e += 256) {
            int tt = e / 76, w = e - tt * 76;
            float v = 0.f;
            if (w < 75) {
                int i = w / 25, vv = w - i * 25;
                int t = tb + tt + i - 1;                 // unfold3 zero-pad
                if (t >= 0 && t < 512)
                    v = b2f(a1c[((size_t)n * 16 + o) * 12800 + t * 25 + vv]);
            }
            ch[e] = v;
        }
        __syncthreads();
        for (int r = 0; r < 64; ++r) {
            const float* row = &ch[r * 76];
            float4 p = *(const float4*)&row[w1a];
            float4 q = *(const float4*)&row[w2a];
            float pa[4] = {p.x, p.y, p.z, p.w}, qa[4] = {q.x, q.y, q.z, q.w};
            #pragma unroll
            for (int i = 0; i < 4; ++i)
                #pragma unroll
                for (int j = 0; j < 4; ++j)
                    acc1[i * 4 + j] = fmaf(pa[i], qa[j], acc1[i * 4 + j]);
            if (two) {
                float4 p2 = *(const float4*)&row[w1b];
                float4 q2 = *(const float4*)&row[w2b];
                float pb[4] = {p2.x, p2.y, p2.z, p2.w}, qb[4] = {q2.x, q2.y, q2.z, q2.w};
                #pragma unroll
                for (int i = 0; i < 4; ++i)
                    #pragma unroll
                    for (int j = 0; j < 4; ++j)
                        acc2[i * 4 + j] = fmaf(pb[i], qb[j], acc2[i * 4 + j]);
            }
        }
    }

    #pragma unroll
    for (int i = 0; i < 4; ++i)
        #pragma unroll
        for (int j = 0; j < 4; ++j) {
            int w1 = w1a + i, w2 = w2a + j;
            if (w1 < 75 && w2 < 75)
                atomicAdd(&attS[(size_t)n * 5625 + w1 * 75 + w2], acc1[i * 4 + j]);
        }
    if (two) {
        #pragma unroll
        for (int i = 0; i < 4; ++i)
            #pragma unroll
            for (int j = 0; j < 4; ++j) {
                int w1 = w1b + i, w2 = w2b + j;
                if (w1 < 75 && w2 < 75)
                    atomicAdd(&attS[(size_t)n * 5625 + w1 * 75 + w2], acc2[i * 4 + j]);
            }
    }
}

// ---------------------------------------------------------------------------
// k2b: scale 1/75, softmax over w1 per column w2.
// ---------------------------------------------------------------------------
__global__ __launch_bounds__(256) void k2b_softmax(
    const float* __restrict__ attS, float* __restrict__ att)
{
    __shared__ float S[5625];
    const int n = blockIdx.x, tid = threadIdx.x;
    for (int e = tid; e < 5625; e += 256)
        S[e] = attS[(size_t)n * 5625 + e] * (1.0f / 75.0f);
    __syncthreads();
    if (tid < 75) {
        const int w2 = tid;
        float m = -1e30f;
        for (int w1 = 0; w1 < 75; ++w1) m = fmaxf(m, S[w1 * 75 + w2]);
        float s = 0.f;
        for (int w1 = 0; w1 < 75; ++w1) {
            float e = __expf(S[w1 * 75 + w2] - m);
            S[w1 * 75 + w2] = e;
            s += e;
        }
        const float r = 1.0f / s;
        for (int w1 = 0; w1 < 75; ++w1)
            att[(size_t)n * 5625 + w1 * 75 + w2] = S[w1 * 75 + w2] * r;
    }
}

// ---------------------------------------------------------------------------
// k3: K=300 contraction, fully LDS-resident operands.
// Block = (n, 8 t's), 320 threads, one 4c x 8w tile each.
// xs [tt*25+v][64ch] staged by coalesced uint4 copy of hcp (t-shift unfold).
// ---------------------------------------------------------------------------
__global__ __launch_bounds__(320, 2) void k3_graph(
    const u16* __restrict__ hcp,
    const float* __restrict__ A, const float* __restrict__ PA,
    const float* __restrict__ att,
    u16* __restrict__ sum12)
{
    __shared__ u16 Bs[300 * 80];   // 48000 B
    __shared__ u16 xs[250 * 64];   // 32000 B
    const int b   = blockIdx.x;
    const int n   = b >> 6;
    const int t0  = (b & 63) << 3;
    const int tid = threadIdx.x;

    for (int e = tid; e < 300 * 80; e += 320) {
        int k = e / 80, w = e - k * 80;
        float v = 0.f;
        if (w < 75) {
            int g = k / 75, w1 = k - g * 75;
            if (g < 3) { int idx = (g * 75 + w1) * 75 + w; v = A[idx] + PA[idx]; }
            else       v = att[(size_t)n * 5625 + w1 * 75 + w];
        }
        Bs[e] = f2b(v);
    }
    for (int q = tid; q < 2000; q += 320) {             // uint4 = 8 ch
        int row = q >> 3, ch8 = (q & 7) << 3;           // row = tt*25+v
        int tt = row / 25, v = row - tt * 25;
        int t = t0 + tt - 1;
        uint4 val; val.x = 0u; val.y = 0u; val.z = 0u; val.w = 0u;
        if (t >= 0 && t < 512)
            val = *(const uint4*)&hcp[((size_t)n * 12800 + t * 25 + v) * 64 + ch8];
        *(uint4*)&xs[row * 64 + ch8] = val;
    }
    __syncthreads();

    const int ts = tid / 40;
    const int r  = tid - ts * 40;
    const int c0 = (r / 10) * 4;
    const int w0 = (r % 10) * 8;

    float acc[4][8];
    #pragma unroll
    for (int i = 0; i < 4; ++i)
        #pragma unroll
        for (int j = 0; j < 8; ++j) acc[i][j] = 0.f;

    #pragma unroll 1
    for (int g = 0; g < 4; ++g) {
        const int chb = (g < 3) ? 16 + g * 16 : 0;      // xs ch = hc_ch - 16
        #pragma unroll 1
        for (int i = 0; i < 3; ++i) {
            const u16* xrow = &xs[(ts + i) * 25 * 64 + chb + c0];
            const u16* brow = &Bs[(g * 75 + i * 25) * 80 + w0];
            #pragma unroll 5
            for (int v1 = 0; v1 < 25; ++v1) {
                float af[4], bf[8];
                unpack4(*(const uint2*)(xrow + v1 * 64), af);
                unpack8(*(const uint4*)(brow + v1 * 80), bf);
                #pragma unroll
                for (int ci = 0; ci < 4; ++ci)
                    #pragma unroll
                    for (int wj = 0; wj < 8; ++wj)
                        acc[ci][wj] = fmaf(af[ci], bf[wj], acc[ci][wj]);
            }
        }
    }

    const int t = t0 + ts;
    #pragma unroll
    for (int i = 0; i < 4; ++i) {
        uint4 s;
        s.x = pack2(acc[i][0], acc[i][1]);
        s.y = pack2(acc[i][2], acc[i][3]);
        s.z = pack2(acc[i][4], acc[i][5]);
        s.w = pack2(acc[i][6], acc[i][7]);
        *(uint4*)&sum12[(((size_t)n * 512 + t) * 16 + c0 + i) * 80 + w0] = s;
    }
}

// ---------------------------------------------------------------------------
// k4: conv3d(1,3,1) + bias + BN + residual + relu.
// ---------------------------------------------------------------------------
__global__ __launch_bounds__(256) void k4_out(
    const u16* __restrict__ sum12,
    const float* __restrict__ ow, const float* __restrict__ obias,
    const float* __restrict__ bg, const float* __restrict__ bb,
    const float* __restrict__ bm, const float* __restrict__ bv,
    const float* __restrict__ x, float* __restrict__ out)
{
    __shared__ float ss[4][16][3][28];
    const int b   = blockIdx.x;
    const int n   = b >> 7;
    const int t0  = (b & 127) << 2;
    const int tid = threadIdx.x;
    const int o   = tid & 63;
    const int ts  = tid >> 6;

    float* sf = &ss[0][0][0][0];
    for (int e = tid; e < 4 * 16 * 3 * 28; e += 256) sf[e] = 0.f;
    __syncthreads();
    for (int e = tid; e < 4 * 16 * 75; e += 256) {
        int ts2 = e / 1200, r = e - ts2 * 1200;
        int c = r / 75, w = r - c * 75;
        int ww = w / 25, v = w - ww * 25;
        ss[ts2][c][ww][v] =
            b2f(sum12[(((size_t)n * 512 + t0 + ts2) * 16 + c) * 80 + w]);
    }
    __syncthreads();

    float wreg[48];
    #pragma unroll
    for (int k = 0; k < 48; ++k) wreg[k] = ow[o * 48 + k];
    const float scale = bg[o] * rsqrtf(bv[o] + 1e-5f);
    const float shift = bb[o] - bm[o] * scale;
    const float obv   = obias[o];

    float accs[25];
    #pragma unroll
    for (int v = 0; v < 25; ++v) accs[v] = 0.f;

    for (int c = 0; c < 16; ++c) {
        #pragma unroll
        for (int ww = 0; ww < 3; ++ww) {
            const float wv = wreg[c * 3 + ww];
            const float* sp = &ss[ts][c][ww][0];
            #pragma unroll
            for (int j = 0; j < 6; ++j) {
                float4 s4 = *(const float4*)&sp[j * 4];
                accs[j * 4 + 0] = fmaf(wv, s4.x, accs[j * 4 + 0]);
                accs[j * 4 + 1] = fmaf(wv, s4.y, accs[j * 4 + 1]);
                accs[j * 4 + 2] = fmaf(wv, s4.z, accs[j * 4 + 2]);
                accs[j * 4 + 3] = fmaf(wv, s4.w, accs[j * 4 + 3]);
            }
            accs[24] = fmaf(wv, sp[24], accs[24]);
        }
    }

    const int t = t0 + ts;
    const size_t base = (((size_t)n * 64 + o) * 512 + t) * 25;
    #pragma unroll
    for (int v = 0; v < 25; ++v) {
        float y = (accs[v] + obv) * scale + shift + x[base + v];
        out[base + v] = fmaxf(y, 0.f);
    }
}

// ---------------------------------------------------------------------------
extern "C" void kernel_launch(void* const* d_in, const int* in_sizes, int n_in,
                              void* d_out, int out_size, void* d_ws, size_t ws_size,
                              hipStream_t stream)
{
    const float* x  = (const float*)d_in[0];
    const float* A  = (const float*)d_in[1];
    const float* PA = (const float*)d_in[2];
    const float* wa = (const float*)d_in[3];
    const float* ba = (const float*)d_in[4];
    const float* wd = (const float*)d_in[5];
    const float* bd = (const float*)d_in[6];
    const float* wc = (const float*)d_in[7];
    const float* bc = (const float*)d_in[8];
    const float* ow = (const float*)d_in[9];
    const float* ob = (const float*)d_in[10];
    const float* bg = (const float*)d_in[11];
    const float* bb = (const float*)d_in[12];
    const float* bm = (const float*)d_in[13];
    const float* bv = (const float*)d_in[14];
    float* out = (float*)d_out;

    char* ws = (char*)d_ws;
    u16*   a1c   = (u16*)(ws);                           // 13,107,200 B
    u16*   hcp   = (u16*)(ws + 13107200);                // 52,428,800 B
    u16*   sum12 = (u16*)(ws + 65536000);                // 41,943,040 B
    float* attS  = (float*)(ws + 107479040);             // 720,000 B
    float* att   = (float*)(ws + 108199040);             // 720,000 B

    hipMemsetAsync(attS, 0, 32 * 5625 * 4, stream);

    k1_conv80 <<<1024, 256, 0, stream>>>(x, wa, ba, wd, bd, wc, bc, a1c, hcp);
    k2a_scores<<<1024, 256, 0, stream>>>(a1c, attS);
    k2b_softmax<<<32,  256, 0, stream>>>(attS, att);
    k3_graph  <<<2048, 320, 0, stream>>>(hcp, A, PA, att, sum12);
    k4_out    <<<4096, 256, 0, stream>>>(sum12, ow, ob, bg, bb, bm, bv, x, out);
}

// Round 3
// 589.901 us; speedup vs baseline: 2.7901x; 1.5701x over previous
//
#include <hip/hip_runtime.h>
#include <hip/hip_bf16.h>

// ============================================================================
// ConvTemporalGraphical — round 3: MFMA k3.
//
//   k0: BtA[80w][288k] bf16 = Aeff^T, K regions r=g*3+i (g=0..2), k=r*32+v,
//       v 25..31 and w 75..79 zero-padded.
//   k1: fused 80-ch 1x1 conv on x. Outputs:
//         a1c [n][16][512*25]            (conv_a, for k2a)
//         hcn [n][cc][512][32]           (cc = g*16+c: g0..2 = x1 groups,
//                                         g3 = xd; v padded to 32, zero-filled)
//       hcn written via LDS transpose epilogue -> coalesced uint4 stores.
//   k2a: attention scores (unfold-on-read), fp32 atomics.
//   k2b: column softmax; writes BtT[n][80w][96k] bf16 = att^T, k=i*32+v padded.
//   k3: MFMA 16x16x32 bf16. Per (n,t): C[16c][80w] = sum_{r=0..11,K32}
//       A[c][k]*B[k][w].  A-frag = one 16B global load from hcn (lane c=lane&15,
//       quad*8 k-offset); Bt staged in LDS [80][392] (pad -> 2-way banks, free).
//       Waves process t-pairs sharing b-frags. C/D: col=lane&15, row=q*4+reg.
//   k4: conv3d(1,3,1) + bias + BN + residual + relu.
//
// ws: a1c 13,107,200 | hcn 67,108,864 | sum12 41,943,040 | attS 720,000 |
//     BtA 46,080 | BtT 491,520  => 123,416,704 B.
// ============================================================================

typedef unsigned short u16;
typedef unsigned int   u32;
typedef __attribute__((ext_vector_type(8))) short bf16x8;
typedef __attribute__((ext_vector_type(4))) float f32x4;

__device__ __forceinline__ float b2f(u32 u) {
    union { u32 i; float f; } x; x.i = (u & 0xffffu) << 16; return x.f;
}
__device__ __forceinline__ u16 f2b(float f) {
    union { float f; u32 i; } x; x.f = f;
    u32 i = x.i;
    return (u16)((i + 0x7fffu + ((i >> 16) & 1u)) >> 16);   // RNE
}
__device__ __forceinline__ u32 pack2(float a, float b) {
    return (u32)f2b(a) | ((u32)f2b(b) << 16);
}
__device__ __forceinline__ void unpack8(uint4 u, float* f) {
    f[0] = b2f(u.x); f[1] = b2f(u.x >> 16);
    f[2] = b2f(u.y); f[3] = b2f(u.y >> 16);
    f[4] = b2f(u.z); f[5] = b2f(u.z >> 16);
    f[6] = b2f(u.w); f[7] = b2f(u.w >> 16);
}

// ---------------------------------------------------------------------------
// k0: BtA = Aeff^T with (g,i)-region K layout, zero-padded.
// ---------------------------------------------------------------------------
__global__ __launch_bounds__(256) void k0_bta(
    const float* __restrict__ A, const float* __restrict__ PA,
    u16* __restrict__ BtA)
{
    int e = blockIdx.x * 256 + threadIdx.x;
    if (e >= 80 * 288) return;
    int w = e / 288, k = e - w * 288;
    int r = k >> 5, v = k & 31, g = r / 3, i = r - g * 3;
    float val = 0.f;
    if (v < 25 && w < 75) {
        int idx = (g * 75 + i * 25 + v) * 75 + w;
        val = A[idx] + PA[idx];
    }
    BtA[e] = f2b(val);
}

// ---------------------------------------------------------------------------
// k1: 80-ch 1x1 conv on x. Block = (n, 16 t's). 250 threads, 8ch x 16tv tiles.
// Epilogue: ch 16..79 round-trip through LDS -> hcn[cc][t][32] coalesced.
// ---------------------------------------------------------------------------
__global__ __launch_bounds__(256, 2) void k1_conv80(
    const float* __restrict__ x,
    const float* __restrict__ wa, const float* __restrict__ ba,
    const float* __restrict__ wd, const float* __restrict__ bd,
    const float* __restrict__ wc, const float* __restrict__ bc,
    u16* __restrict__ a1c, u16* __restrict__ hcn)
{
    __shared__ u16 Wl[64 * 80];     // [c][o]
    __shared__ u16 xsh[64 * 400];   // [c][tv]; epilogue: hsh[64 rows][400]
    const int b   = blockIdx.x;
    const int n   = b >> 5;
    const int t0  = (b & 31) << 4;
    const int tid = threadIdx.x;

    for (int e = tid; e < 64 * 80; e += 256) {
        int c = e / 80, o = e - c * 80;
        float v;
        if (o < 16)      v = wa[o * 64 + c];
        else if (o < 32) v = wd[(o - 16) * 64 + c];
        else             v = wc[(o - 32) * 64 + c];
        Wl[e] = f2b(v);
    }
    for (int idx = tid; idx < 6400; idx += 256) {       // 100 float4 per c
        int c = idx / 100, r4 = idx - c * 100;
        const float4 v = *(const float4*)&x[(((size_t)n * 64 + c) * 512 + t0) * 25 + r4 * 4];
        *(u32*)&xsh[c * 400 + r4 * 4]     = pack2(v.x, v.y);
        *(u32*)&xsh[c * 400 + r4 * 4 + 2] = pack2(v.z, v.w);
    }
    __syncthreads();

    float acc[8][16];
    int ch0 = 0, n0 = 0;
    if (tid < 250) {
        ch0 = (tid / 25) * 8;
        n0  = (tid % 25) * 16;
        #pragma unroll
        for (int i = 0; i < 8; ++i)
            #pragma unroll
            for (int j = 0; j < 16; ++j) acc[i][j] = 0.f;

        #pragma unroll 4
        for (int c = 0; c < 64; ++c) {
            float wf[8], xf[16];
            unpack8(*(const uint4*)&Wl[c * 80 + ch0], wf);
            unpack8(*(const uint4*)&xsh[c * 400 + n0], xf);
            unpack8(*(const uint4*)&xsh[c * 400 + n0 + 8], xf + 8);
            #pragma unroll
            for (int i = 0; i < 8; ++i)
                #pragma unroll
                for (int j = 0; j < 16; ++j)
                    acc[i][j] = fmaf(wf[i], xf[j], acc[i][j]);
        }
    }
    __syncthreads();                                    // xsh reads done

    if (tid < 250 && ch0 >= 16) {                       // hc -> LDS (bf16)
        const int row0 = ch0 - 16;
        #pragma unroll
        for (int i = 0; i < 8; ++i) {
            const int ch = ch0 + i;
            const float bi = (ch < 32) ? bd[ch - 16] : bc[ch - 32];
            const int base = (row0 + i) * 400 + n0;
            #pragma unroll
            for (int jj = 0; jj < 8; ++jj)
                *(u32*)&xsh[base + 2 * jj] =
                    pack2(acc[i][2 * jj] + bi, acc[i][2 * jj + 1] + bi);
        }
    }
    if (tid < 250 && ch0 < 16) {                        // a1c direct
        #pragma unroll
        for (int i = 0; i < 8; ++i) {
            const int o = ch0 + i;
            const float bias = ba[o];
            size_t base = ((size_t)n * 16 + o) * 12800 + t0 * 25 + n0;
            uint4 s0, s1;
            s0.x = pack2(acc[i][0] + bias,  acc[i][1] + bias);
            s0.y = pack2(acc[i][2] + bias,  acc[i][3] + bias);
            s0.z = pack2(acc[i][4] + bias,  acc[i][5] + bias);
            s0.w = pack2(acc[i][6] + bias,  acc[i][7] + bias);
            s1.x = pack2(acc[i][8] + bias,  acc[i][9] + bias);
            s1.y = pack2(acc[i][10] + bias, acc[i][11] + bias);
            s1.z = pack2(acc[i][12] + bias, acc[i][13] + bias);
            s1.w = pack2(acc[i][14] + bias, acc[i][15] + bias);
            *(uint4*)&a1c[base]     = s0;
            *(uint4*)&a1c[base + 8] = s1;
        }
    }
    __syncthreads();

    // hcn stores: 64 rows x 16 t x 4 uint4-chunks (v padded to 32, zeros).
    for (int e = tid; e < 4096; e += 256) {
        const int cc64 = e >> 6, rem = e & 63;
        const int tl = rem >> 2, v0 = (rem & 3) << 3;
        u16 vals[8];
        #pragma unroll
        for (int h = 0; h < 8; ++h) {
            int v = v0 + h;
            vals[h] = (v < 25) ? xsh[cc64 * 400 + tl * 25 + v] : (u16)0;
        }
        uint4 pk;
        pk.x = (u32)vals[0] | ((u32)vals[1] << 16);
        pk.y = (u32)vals[2] | ((u32)vals[3] << 16);
        pk.z = (u32)vals[4] | ((u32)vals[5] << 16);
        pk.w = (u32)vals[6] | ((u32)vals[7] << 16);
        const int cc = (cc64 < 16) ? 48 + cc64 : cc64 - 16;   // xd -> g3
        *(uint4*)&hcn[(((size_t)n * 64 + cc) * 512 + (t0 + tl)) * 32 + v0] = pk;
    }
}

// ---------------------------------------------------------------------------
// k2a: S[n][w1][w2] += sum_{o, 256 t's} a1[w1]*a1[w2], unfold-on-read,
// fp32 atomics. Block = (n, o, t-half).
// ---------------------------------------------------------------------------
__global__ __launch_bounds__(256) void k2a_scores(
    const u16* __restrict__ a1c, float* __restrict__ attS)
{
    __shared__ float ch[64 * 76];
    const int b   = blockIdx.x;
    const int n   = b >> 5;
    const int o   = (b & 31) >> 1;
    const int th  = b & 1;
    const int tid = threadIdx.x;

    const bool two = (tid < 105);
    const int w1a = (tid / 19) * 4, w2a = (tid % 19) * 4;
    const int w1b = ((tid + 256) / 19) * 4, w2b = ((tid + 256) % 19) * 4;

    float acc1[16], acc2[16];
    #pragma unroll
    for (int i = 0; i < 16; ++i) { acc1[i] = 0.f; acc2[i] = 0.f; }

    for (int ch0 = 0; ch0 < 4; ++ch0) {
        __syncthreads();
        const int tb = th * 256 + ch0 * 64;
        for (int e = tid; e < 64 * 76; e += 256) {
            int tt = e / 76, w = e - tt * 76;
            float v = 0.f;
            if (w < 75) {
                int i = w / 25, vv = w - i * 25;
                int t = tb + tt + i - 1;                 // unfold3 zero-pad
                if (t >= 0 && t < 512)
                    v = b2f(a1c[((size_t)n * 16 + o) * 12800 + t * 25 + vv]);
            }
            ch[e] = v;
        }
        __syncthreads();
        for (int r = 0; r < 64; ++r) {
            const float* row = &ch[r * 76];
            float4 p = *(const float4*)&row[w1a];
            float4 q = *(const float4*)&row[w2a];
            float pa[4] = {p.x, p.y, p.z, p.w}, qa[4] = {q.x, q.y, q.z, q.w};
            #pragma unroll
            for (int i = 0; i < 4; ++i)
                #pragma unroll
                for (int j = 0; j < 4; ++j)
                    acc1[i * 4 + j] = fmaf(pa[i], qa[j], acc1[i * 4 + j]);
            if (two) {
                float4 p2 = *(const float4*)&row[w1b];
                float4 q2 = *(const float4*)&row[w2b];
                float pb[4] = {p2.x, p2.y, p2.z, p2.w}, qb[4] = {q2.x, q2.y, q2.z, q2.w};
                #pragma unroll
                for (int i = 0; i < 4; ++i)
                    #pragma unroll
                    for (int j = 0; j < 4; ++j)
                        acc2[i * 4 + j] = fmaf(pb[i], qb[j], acc2[i * 4 + j]);
            }
        }
    }

    #pragma unroll
    for (int i = 0; i < 4; ++i)
        #pragma unroll
        for (int j = 0; j < 4; ++j) {
            int w1 = w1a + i, w2 = w2a + j;
            if (w1 < 75 && w2 < 75)
                atomicAdd(&attS[(size_t)n * 5625 + w1 * 75 + w2], acc1[i * 4 + j]);
        }
    if (two) {
        #pragma unroll
        for (int i = 0; i < 4; ++i)
            #pragma unroll
            for (int j = 0; j < 4; ++j) {
                int w1 = w1b + i, w2 = w2b + j;
                if (w1 < 75 && w2 < 75)
                    atomicAdd(&attS[(size_t)n * 5625 + w1 * 75 + w2], acc2[i * 4 + j]);
            }
    }
}

// ---------------------------------------------------------------------------
// k2b: scale 1/75, softmax over w1 per column w2; write att^T padded bf16.
// ---------------------------------------------------------------------------
__global__ __launch_bounds__(256) void k2b_softmax(
    const float* __restrict__ attS, u16* __restrict__ BtT)
{
    __shared__ float S[5625];
    const int n = blockIdx.x, tid = threadIdx.x;
    for (int e = tid; e < 5625; e += 256)
        S[e] = attS[(size_t)n * 5625 + e] * (1.0f / 75.0f);
    __syncthreads();
    if (tid < 80) {
        const int w2 = tid;
        float r = 0.f;
        if (w2 < 75) {
            float m = -1e30f;
            for (int w1 = 0; w1 < 75; ++w1) m = fmaxf(m, S[w1 * 75 + w2]);
            float s = 0.f;
            for (int w1 = 0; w1 < 75; ++w1) {
                float e = __expf(S[w1 * 75 + w2] - m);
                S[w1 * 75 + w2] = e;                  // own column
                s += e;
            }
            r = 1.0f / s;
        }
        for (int k = 0; k < 96; ++k) {
            int i = k >> 5, v = k & 31;
            float val = (w2 < 75 && v < 25) ? S[(i * 25 + v) * 75 + w2] * r : 0.f;
            BtT[((size_t)n * 80 + w2) * 96 + k] = f2b(val);
        }
    }
}

// ---------------------------------------------------------------------------
// k3: MFMA graph contraction. Block = (n, 32 t's), 4 waves x 8 t's (pairs).
// ---------------------------------------------------------------------------
__global__ __launch_bounds__(256, 2) void k3_graph(
    const u16* __restrict__ hcn, const u16* __restrict__ BtA,
    const u16* __restrict__ BtT, u16* __restrict__ sum12)
{
    __shared__ u16 Bt[80 * 392];   // row stride 392 u16 = 784 B (2-way banks)
    const int b    = blockIdx.x;
    const int n    = b >> 4;
    const int tblk = (b & 15) << 5;
    const int tid  = threadIdx.x;

    for (int e = tid; e < 3840; e += 256) {             // stage Bt (uint4)
        int row = e / 48, cs = e - row * 48;
        uint4 val;
        if (cs < 36) val = *(const uint4*)&BtA[row * 288 + cs * 8];
        else         val = *(const uint4*)&BtT[((size_t)n * 80 + row) * 96 + (cs - 36) * 8];
        *(uint4*)&Bt[row * 392 + cs * 8] = val;
    }
    __syncthreads();

    const int wave = tid >> 6, lane = tid & 63;
    const int c = lane & 15, q = lane >> 4;
    const int tb = tblk + wave * 8;

    for (int tt = 0; tt < 8; tt += 2) {
        const int t0 = tb + tt, t1 = t0 + 1;
        bf16x8 a0[12], a1[12];
        #pragma unroll
        for (int r = 0; r < 12; ++r) {
            const int g = r / 3, i = r - g * 3;
            const size_t rowb = ((size_t)n * 64 + g * 16 + c) * 512;
            const int tp0 = t0 + i - 1, tp1 = t1 + i - 1;
            a0[r] = (tp0 >= 0 && tp0 < 512)
                  ? *(const bf16x8*)&hcn[(rowb + tp0) * 32 + q * 8] : (bf16x8)(short)0;
            a1[r] = (tp1 >= 0 && tp1 < 512)
                  ? *(const bf16x8*)&hcn[(rowb + tp1) * 32 + q * 8] : (bf16x8)(short)0;
        }
        #pragma unroll 1
        for (int nt = 0; nt < 5; ++nt) {
            f32x4 acc0 = {0.f, 0.f, 0.f, 0.f};
            f32x4 acc1 = {0.f, 0.f, 0.f, 0.f};
            const u16* bp = &Bt[(nt * 16 + c) * 392 + q * 8];
            #pragma unroll
            for (int r = 0; r < 12; ++r) {
                bf16x8 bf = *(const bf16x8*)(bp + r * 32);
                acc0 = __builtin_amdgcn_mfma_f32_16x16x32_bf16(a0[r], bf, acc0, 0, 0, 0);
                acc1 = __builtin_amdgcn_mfma_f32_16x16x32_bf16(a1[r], bf, acc1, 0, 0, 0);
            }
            // C/D: col = lane&15 (w), row = q*4+reg (c)
            const size_t ob0 = (((size_t)n * 512 + t0) * 16) * 80 + nt * 16 + c;
            const size_t ob1 = (((size_t)n * 512 + t1) * 16) * 80 + nt * 16 + c;
            #pragma unroll
            for (int reg = 0; reg < 4; ++reg) {
                sum12[ob0 + (size_t)(q * 4 + reg) * 80] = f2b(acc0[reg]);
                sum12[ob1 + (size_t)(q * 4 + reg) * 80] = f2b(acc1[reg]);
            }
        }
    }
}

// ---------------------------------------------------------------------------
// k4: conv3d(1,3,1) + bias + BN + residual + relu.
// ---------------------------------------------------------------------------
__global__ __launch_bounds__(256) void k4_out(
    const u16* __restrict__ sum12,
    const float* __restrict__ ow, const float* __restrict__ obias,
    const float* __restrict__ bg, const float* __restrict__ bb,
    const float* __restrict__ bm, const float* __restrict__ bv,
    const float* __restrict__ x, float* __restrict__ out)
{
    __shared__ float ss[4][16][3][28];
    const int b   = blockIdx.x;
    const int n   = b >> 7;
    const int t0  = (b & 127) << 2;
    const int tid = threadIdx.x;
    const int o   = tid & 63;
    const int ts  = tid >> 6;

    float* sf = &ss[0][0][0][0];
    for (int e = tid; e < 4 * 16 * 3 * 28; e += 256) sf[e] = 0.f;
    __syncthreads();
    for (int e = tid; e < 4 * 16 * 75; e += 256) {
        int ts2 = e / 1200, r = e - ts2 * 1200;
        int c = r / 75, w = r - c * 75;
        int ww = w / 25, v = w - ww * 25;
        ss[ts2][c][ww][v] =
            b2f(sum12[(((size_t)n * 512 + t0 + ts2) * 16 + c) * 80 + w]);
    }
    __syncthreads();

    float wreg[48];
    #pragma unroll
    for (int k = 0; k < 48; ++k) wreg[k] = ow[o * 48 + k];
    const float scale = bg[o] * rsqrtf(bv[o] + 1e-5f);
    const float shift = bb[o] - bm[o] * scale;
    const float obv   = obias[o];

    float accs[25];
    #pragma unroll
    for (int v = 0; v < 25; ++v) accs[v] = 0.f;

    for (int c = 0; c < 16; ++c) {
        #pragma unroll
        for (int ww = 0; ww < 3; ++ww) {
            const float wv = wreg[c * 3 + ww];
            const float* sp = &ss[ts][c][ww][0];
            #pragma unroll
            for (int j = 0; j < 6; ++j) {
                float4 s4 = *(const float4*)&sp[j * 4];
                accs[j * 4 + 0] = fmaf(wv, s4.x, accs[j * 4 + 0]);
                accs[j * 4 + 1] = fmaf(wv, s4.y, accs[j * 4 + 1]);
                accs[j * 4 + 2] = fmaf(wv, s4.z, accs[j * 4 + 2]);
                accs[j * 4 + 3] = fmaf(wv, s4.w, accs[j * 4 + 3]);
            }
            accs[24] = fmaf(wv, sp[24], accs[24]);
        }
    }

    const int t = t0 + ts;
    const size_t base = (((size_t)n * 64 + o) * 512 + t) * 25;
    #pragma unroll
    for (int v = 0; v < 25; ++v) {
        float y = (accs[v] + obv) * scale + shift + x[base + v];
        out[base + v] = fmaxf(y, 0.f);
    }
}

// ---------------------------------------------------------------------------
extern "C" void kernel_launch(void* const* d_in, const int* in_sizes, int n_in,
                              void* d_out, int out_size, void* d_ws, size_t ws_size,
                              hipStream_t stream)
{
    const float* x  = (const float*)d_in[0];
    const float* A  = (const float*)d_in[1];
    const float* PA = (const float*)d_in[2];
    const float* wa = (const float*)d_in[3];
    const float* ba = (const float*)d_in[4];
    const float* wd = (const float*)d_in[5];
    const float* bd = (const float*)d_in[6];
    const float* wc = (const float*)d_in[7];
    const float* bc = (const float*)d_in[8];
    const float* ow = (const float*)d_in[9];
    const float* ob = (const float*)d_in[10];
    const float* bg = (const float*)d_in[11];
    const float* bb = (const float*)d_in[12];
    const float* bm = (const float*)d_in[13];
    const float* bv = (const float*)d_in[14];
    float* out = (float*)d_out;

    char* ws = (char*)d_ws;
    u16*   a1c   = (u16*)(ws);                           // 13,107,200 B
    u16*   hcn   = (u16*)(ws + 13107200);                // 67,108,864 B
    u16*   sum12 = (u16*)(ws + 80216064);                // 41,943,040 B
    float* attS  = (float*)(ws + 122159104);             // 720,000 B
    u16*   BtA   = (u16*)(ws + 122879104);               // 46,080 B
    u16*   BtT   = (u16*)(ws + 122925184);               // 491,520 B

    hipMemsetAsync(attS, 0, 32 * 5625 * 4, stream);

    k0_bta    <<<90,   256, 0, stream>>>(A, PA, BtA);
    k1_conv80 <<<1024, 256, 0, stream>>>(x, wa, ba, wd, bd, wc, bc, a1c, hcn);
    k2a_scores<<<1024, 256, 0, stream>>>(a1c, attS);
    k2b_softmax<<<32,  256, 0, stream>>>(attS, BtT);
    k3_graph  <<<512,  256, 0, stream>>>(hcn, BtA, BtT, sum12);
    k4_out    <<<4096, 256, 0, stream>>>(sum12, ow, ob, bg, bb, bm, bv, x, out);
}

// Round 4
// 504.988 us; speedup vs baseline: 3.2592x; 1.1681x over previous
//
#include <hip/hip_runtime.h>
#include <hip/hip_bf16.h>

// ============================================================================
// ConvTemporalGraphical — round 4: MFMA k2a (Gram matrix), no atomics.
//
//   k0: BtA[80w][288k] = Aeff^T bf16, K regions r=g*3+i, k=r*32+v (padded).
//   k1: fused 80-ch 1x1 conv on x. Outputs:
//         a1o [n][514][25][16]  (conv_a out, t padded +1 both sides, o-inner —
//                                16B-aligned frag rows for k2a regardless of
//                                the unfold t-shift)
//         hcn [n][cc][512][32]  (for k3; v padded to 32)
//   k2a: MFMA Gram: S[w1][w2] = sum_{o,t} a1u[w1][k] a1u[w2][k], k=t*16+o.
//        Block=(n, 32-t chunk): U[80][136] bf16 staged per 8-t stage; A-frag ==
//        B-frag (same rows) -> 5 ds_read_b128 per 25 MFMAs. Cross-wave LDS
//        reduce -> Spart[n][16][80][80] fp32, NO atomics.
//   k2b: sum 16 partials, /75, column softmax, write BtT[n][80][96] = att^T.
//   k3: MFMA 16x16x32 graph contraction (unchanged from round 3).
//   k4: conv3d(1,3,1) + bias + BN + residual + relu (unchanged).
//
// ws: a1o 13,158,400 | hcn 67,108,864 | sum12 41,943,040 | BtA 46,080 |
//     BtT 491,520 | Spart 13,107,200  => 135,855,104 B.
// ============================================================================

typedef unsigned short u16;
typedef unsigned int   u32;
typedef __attribute__((ext_vector_type(8))) short bf16x8;
typedef __attribute__((ext_vector_type(4))) float f32x4;

__device__ __forceinline__ float b2f(u32 u) {
    union { u32 i; float f; } x; x.i = (u & 0xffffu) << 16; return x.f;
}
__device__ __forceinline__ u16 f2b(float f) {
    union { float f; u32 i; } x; x.f = f;
    u32 i = x.i;
    return (u16)((i + 0x7fffu + ((i >> 16) & 1u)) >> 16);   // RNE
}
__device__ __forceinline__ u32 pack2(float a, float b) {
    return (u32)f2b(a) | ((u32)f2b(b) << 16);
}
__device__ __forceinline__ void unpack8(uint4 u, float* f) {
    f[0] = b2f(u.x); f[1] = b2f(u.x >> 16);
    f[2] = b2f(u.y); f[3] = b2f(u.y >> 16);
    f[4] = b2f(u.z); f[5] = b2f(u.z >> 16);
    f[6] = b2f(u.w); f[7] = b2f(u.w >> 16);
}

// ---------------------------------------------------------------------------
// k0: BtA = Aeff^T with (g,i)-region K layout, zero-padded.
// ---------------------------------------------------------------------------
__global__ __launch_bounds__(256) void k0_bta(
    const float* __restrict__ A, const float* __restrict__ PA,
    u16* __restrict__ BtA)
{
    int e = blockIdx.x * 256 + threadIdx.x;
    if (e >= 80 * 288) return;
    int w = e / 288, k = e - w * 288;
    int r = k >> 5, v = k & 31, g = r / 3, i = r - g * 3;
    float val = 0.f;
    if (v < 25 && w < 75) {
        int idx = (g * 75 + i * 25 + v) * 75 + w;
        val = A[idx] + PA[idx];
    }
    BtA[e] = f2b(val);
}

// ---------------------------------------------------------------------------
// k1: 80-ch 1x1 conv on x. Block = (n, 16 t's). 250 threads, 8ch x 16tv tiles.
// Epilogues: ch16..79 -> hcn via xsh transpose; ch0..15 -> a1o via ash.
// ---------------------------------------------------------------------------
__global__ __launch_bounds__(256, 2) void k1_conv80(
    const float* __restrict__ x,
    const float* __restrict__ wa, const float* __restrict__ ba,
    const float* __restrict__ wd, const float* __restrict__ bd,
    const float* __restrict__ wc, const float* __restrict__ bc,
    u16* __restrict__ a1o, u16* __restrict__ hcn)
{
    __shared__ u16 Wl[64 * 80];     // [c][o]
    __shared__ u16 xsh[64 * 400];   // [c][tv]; epilogue: hc rows
    __shared__ u16 ash[16 * 400];   // [o][tv] for a1
    const int b   = blockIdx.x;
    const int n   = b >> 5;
    const int t0  = (b & 31) << 4;
    const int tid = threadIdx.x;

    for (int e = tid; e < 64 * 80; e += 256) {
        int c = e / 80, o = e - c * 80;
        float v;
        if (o < 16)      v = wa[o * 64 + c];
        else if (o < 32) v = wd[(o - 16) * 64 + c];
        else             v = wc[(o - 32) * 64 + c];
        Wl[e] = f2b(v);
    }
    for (int idx = tid; idx < 6400; idx += 256) {       // 100 float4 per c
        int c = idx / 100, r4 = idx - c * 100;
        const float4 v = *(const float4*)&x[(((size_t)n * 64 + c) * 512 + t0) * 25 + r4 * 4];
        *(u32*)&xsh[c * 400 + r4 * 4]     = pack2(v.x, v.y);
        *(u32*)&xsh[c * 400 + r4 * 4 + 2] = pack2(v.z, v.w);
    }
    __syncthreads();

    float acc[8][16];
    int ch0 = 0, n0 = 0;
    if (tid < 250) {
        ch0 = (tid / 25) * 8;
        n0  = (tid % 25) * 16;
        #pragma unroll
        for (int i = 0; i < 8; ++i)
            #pragma unroll
            for (int j = 0; j < 16; ++j) acc[i][j] = 0.f;

        #pragma unroll 4
        for (int c = 0; c < 64; ++c) {
            float wf[8], xf[16];
            unpack8(*(const uint4*)&Wl[c * 80 + ch0], wf);
            unpack8(*(const uint4*)&xsh[c * 400 + n0], xf);
            unpack8(*(const uint4*)&xsh[c * 400 + n0 + 8], xf + 8);
            #pragma unroll
            for (int i = 0; i < 8; ++i)
                #pragma unroll
                for (int j = 0; j < 16; ++j)
                    acc[i][j] = fmaf(wf[i], xf[j], acc[i][j]);
        }
    }
    __syncthreads();                                    // xsh reads done

    if (tid < 250 && ch0 >= 16) {                       // hc -> xsh (bf16)
        const int row0 = ch0 - 16;
        #pragma unroll
        for (int i = 0; i < 8; ++i) {
            const int ch = ch0 + i;
            const float bi = (ch < 32) ? bd[ch - 16] : bc[ch - 32];
            const int base = (row0 + i) * 400 + n0;
            #pragma unroll
            for (int jj = 0; jj < 8; ++jj)
                *(u32*)&xsh[base + 2 * jj] =
                    pack2(acc[i][2 * jj] + bi, acc[i][2 * jj + 1] + bi);
        }
    }
    if (tid < 250 && ch0 < 16) {                        // a1 -> ash [o][tv]
        #pragma unroll
        for (int i = 0; i < 8; ++i) {
            const int o = ch0 + i;
            const float bias = ba[o];
            #pragma unroll
            for (int j = 0; j < 16; ++j)
                ash[o * 400 + n0 + j] = f2b(acc[i][j] + bias);
        }
    }
    __syncthreads();

    // hcn stores: 64 rows x 16 t x 4 uint4-chunks (v padded to 32, zeros).
    for (int e = tid; e < 4096; e += 256) {
        const int cc64 = e >> 6, rem = e & 63;
        const int tl = rem >> 2, v0 = (rem & 3) << 3;
        u16 vals[8];
        #pragma unroll
        for (int h = 0; h < 8; ++h) {
            int v = v0 + h;
            vals[h] = (v < 25) ? xsh[cc64 * 400 + tl * 25 + v] : (u16)0;
        }
        uint4 pk;
        pk.x = (u32)vals[0] | ((u32)vals[1] << 16);
        pk.y = (u32)vals[2] | ((u32)vals[3] << 16);
        pk.z = (u32)vals[4] | ((u32)vals[5] << 16);
        pk.w = (u32)vals[6] | ((u32)vals[7] << 16);
        const int cc = (cc64 < 16) ? 48 + cc64 : cc64 - 16;   // xd -> g3
        *(uint4*)&hcn[(((size_t)n * 64 + cc) * 512 + (t0 + tl)) * 32 + v0] = pk;
    }

    // a1o stores: [n][t0+tl+1][v][16o], 800 uint4 chunks (o-transposed).
    for (int e = tid; e < 800; e += 256) {
        const int tv = e >> 1, h = (e & 1) << 3;
        const int tl = tv / 25, v = tv - tl * 25;
        u32 p0 = (u32)ash[(h + 0) * 400 + tv] | ((u32)ash[(h + 1) * 400 + tv] << 16);
        u32 p1 = (u32)ash[(h + 2) * 400 + tv] | ((u32)ash[(h + 3) * 400 + tv] << 16);
        u32 p2 = (u32)ash[(h + 4) * 400 + tv] | ((u32)ash[(h + 5) * 400 + tv] << 16);
        u32 p3 = (u32)ash[(h + 6) * 400 + tv] | ((u32)ash[(h + 7) * 400 + tv] << 16);
        uint4 pk; pk.x = p0; pk.y = p1; pk.z = p2; pk.w = p3;
        *(uint4*)&a1o[(((size_t)n * 514 + (t0 + tl + 1)) * 25 + v) * 16 + h] = pk;
    }
    // zero the t-pad rows (ws is poisoned each launch)
    if (t0 == 0) {
        uint4 z; z.x = 0u; z.y = 0u; z.z = 0u; z.w = 0u;
        for (int e = tid; e < 50; e += 256)
            *(uint4*)&a1o[((size_t)n * 514) * 400 + e * 8] = z;
    }
    if (t0 == 496) {
        uint4 z; z.x = 0u; z.y = 0u; z.z = 0u; z.w = 0u;
        for (int e = tid; e < 50; e += 256)
            *(uint4*)&a1o[((size_t)n * 514 + 513) * 400 + e * 8] = z;
    }
}

// ---------------------------------------------------------------------------
// k2a: MFMA Gram matrix. Block = (n, 32-t chunk), 4 waves split k.
// U rows w=i*25+v, cols kk=tl*16+o. A-frag == B-frag (same matrix).
// ---------------------------------------------------------------------------
__global__ __launch_bounds__(256, 2) void k2a_mfma(
    const u16* __restrict__ a1o, float* __restrict__ Spart)
{
    __shared__ u16 U[80 * 136];        // 21,760 B (stride 136: 2-way banks)
    __shared__ float Sred[80 * 80];    // 25,600 B
    const int b   = blockIdx.x;
    const int n   = b >> 4;
    const int tc  = b & 15;
    const int t0  = tc * 32;
    const int tid = threadIdx.x;
    const int wave = tid >> 6, lane = tid & 63;
    const int q = lane >> 4, col = lane & 15;

    f32x4 acc[25];
    #pragma unroll
    for (int i = 0; i < 25; ++i) acc[i] = (f32x4){0.f, 0.f, 0.f, 0.f};

    for (int s = 0; s < 4; ++s) {
        __syncthreads();                               // prior reads done
        for (int e = tid; e < 1280; e += 256) {        // stage 8 t's
            int row = e >> 4, c8 = (e & 15) << 3;
            uint4 val; val.x = 0u; val.y = 0u; val.z = 0u; val.w = 0u;
            if (row < 75) {
                int i = row / 25, v = row - i * 25;
                int tl = c8 >> 4, o0 = c8 & 8;
                int tp = t0 + s * 8 + tl + i;          // padded t idx, 0..513
                val = *(const uint4*)&a1o[(((size_t)n * 514 + tp) * 25 + v) * 16 + o0];
            }
            *(uint4*)&U[row * 136 + c8] = val;
        }
        __syncthreads();

        const int k0 = wave * 32 + q * 8;
        bf16x8 fr[5];
        #pragma unroll
        for (int r = 0; r < 5; ++r)
            fr[r] = *(const bf16x8*)&U[(r * 16 + col) * 136 + k0];
        #pragma unroll
        for (int mt = 0; mt < 5; ++mt)
            #pragma unroll
            for (int nt = 0; nt < 5; ++nt)
                acc[mt * 5 + nt] = __builtin_amdgcn_mfma_f32_16x16x32_bf16(
                    fr[mt], fr[nt], acc[mt * 5 + nt], 0, 0, 0);
    }

    // cross-wave reduce into Sred (C/D: row = q*4+reg, col = lane&15)
    for (int w = 0; w < 4; ++w) {
        if (wave == w) {
            #pragma unroll
            for (int mt = 0; mt < 5; ++mt)
                #pragma unroll
                for (int nt = 0; nt < 5; ++nt)
                    #pragma unroll
                    for (int reg = 0; reg < 4; ++reg) {
                        int idx = (mt * 16 + q * 4 + reg) * 80 + nt * 16 + col;
                        if (w == 0) Sred[idx]  = acc[mt * 5 + nt][reg];
                        else        Sred[idx] += acc[mt * 5 + nt][reg];
                    }
        }
        __syncthreads();
    }
    float* dst = &Spart[(size_t)(n * 16 + tc) * 6400];
    for (int e = tid; e < 6400; e += 256) dst[e] = Sred[e];
}

// ---------------------------------------------------------------------------
// k2b: sum 16 partials, /75, column softmax over w1; write att^T padded bf16.
// ---------------------------------------------------------------------------
__global__ __launch_bounds__(256) void k2b_softmax(
    const float* __restrict__ Spart, u16* __restrict__ BtT)
{
    __shared__ float S[6400];
    const int n = blockIdx.x, tid = threadIdx.x;
    for (int e = tid; e < 6400; e += 256) {
        float s = 0.f;
        for (int ks = 0; ks < 16; ++ks)
            s += Spart[(size_t)(n * 16 + ks) * 6400 + e];
        S[e] = s * (1.0f / 75.0f);
    }
    __syncthreads();
    if (tid < 80) {
        const int w2 = tid;
        float r = 0.f;
        if (w2 < 75) {
            float m = -1e30f;
            for (int w1 = 0; w1 < 75; ++w1) m = fmaxf(m, S[w1 * 80 + w2]);
            float s = 0.f;
            for (int w1 = 0; w1 < 75; ++w1) {
                float e = __expf(S[w1 * 80 + w2] - m);
                S[w1 * 80 + w2] = e;                  // own column
                s += e;
            }
            r = 1.0f / s;
        }
        for (int k = 0; k < 96; ++k) {
            int i = k >> 5, v = k & 31;
            float val = (w2 < 75 && v < 25) ? S[(i * 25 + v) * 80 + w2] * r : 0.f;
            BtT[((size_t)n * 80 + w2) * 96 + k] = f2b(val);
        }
    }
}

// ---------------------------------------------------------------------------
// k3: MFMA graph contraction. Block = (n, 32 t's), 4 waves x 8 t's (pairs).
// ---------------------------------------------------------------------------
__global__ __launch_bounds__(256, 2) void k3_graph(
    const u16* __restrict__ hcn, const u16* __restrict__ BtA,
    const u16* __restrict__ BtT, u16* __restrict__ sum12)
{
    __shared__ u16 Bt[80 * 392];   // row stride 392 u16 = 784 B (2-way banks)
    const int b    = blockIdx.x;
    const int n    = b >> 4;
    const int tblk = (b & 15) << 5;
    const int tid  = threadIdx.x;

    for (int e = tid; e < 3840; e += 256) {             // stage Bt (uint4)
        int row = e / 48, cs = e - row * 48;
        uint4 val;
        if (cs < 36) val = *(const uint4*)&BtA[row * 288 + cs * 8];
        else         val = *(const uint4*)&BtT[((size_t)n * 80 + row) * 96 + (cs - 36) * 8];
        *(uint4*)&Bt[row * 392 + cs * 8] = val;
    }
    __syncthreads();

    const int wave = tid >> 6, lane = tid & 63;
    const int c = lane & 15, q = lane >> 4;
    const int tb = tblk + wave * 8;

    for (int tt = 0; tt < 8; tt += 2) {
        const int t0 = tb + tt, t1 = t0 + 1;
        bf16x8 a0[12], a1[12];
        #pragma unroll
        for (int r = 0; r < 12; ++r) {
            const int g = r / 3, i = r - g * 3;
            const size_t rowb = ((size_t)n * 64 + g * 16 + c) * 512;
            const int tp0 = t0 + i - 1, tp1 = t1 + i - 1;
            a0[r] = (tp0 >= 0 && tp0 < 512)
                  ? *(const bf16x8*)&hcn[(rowb + tp0) * 32 + q * 8] : (bf16x8)(short)0;
            a1[r] = (tp1 >= 0 && tp1 < 512)
                  ? *(const bf16x8*)&hcn[(rowb + tp1) * 32 + q * 8] : (bf16x8)(short)0;
        }
        #pragma unroll 1
        for (int nt = 0; nt < 5; ++nt) {
            f32x4 acc0 = {0.f, 0.f, 0.f, 0.f};
            f32x4 acc1 = {0.f, 0.f, 0.f, 0.f};
            const u16* bp = &Bt[(nt * 16 + c) * 392 + q * 8];
            #pragma unroll
            for (int r = 0; r < 12; ++r) {
                bf16x8 bf = *(const bf16x8*)(bp + r * 32);
                acc0 = __builtin_amdgcn_mfma_f32_16x16x32_bf16(a0[r], bf, acc0, 0, 0, 0);
                acc1 = __builtin_amdgcn_mfma_f32_16x16x32_bf16(a1[r], bf, acc1, 0, 0, 0);
            }
            // C/D: col = lane&15 (w), row = q*4+reg (c)
            const size_t ob0 = (((size_t)n * 512 + t0) * 16) * 80 + nt * 16 + c;
            const size_t ob1 = (((size_t)n * 512 + t1) * 16) * 80 + nt * 16 + c;
            #pragma unroll
            for (int reg = 0; reg < 4; ++reg) {
                sum12[ob0 + (size_t)(q * 4 + reg) * 80] = f2b(acc0[reg]);
                sum12[ob1 + (size_t)(q * 4 + reg) * 80] = f2b(acc1[reg]);
            }
        }
    }
}

// ---------------------------------------------------------------------------
// k4: conv3d(1,3,1) + bias + BN + residual + relu.
// ---------------------------------------------------------------------------
__global__ __launch_bounds__(256) void k4_out(
    const u16* __restrict__ sum12,
    const float* __restrict__ ow, const float* __restrict__ obias,
    const float* __restrict__ bg, const float* __restrict__ bb,
    const float* __restrict__ bm, const float* __restrict__ bv,
    const float* __restrict__ x, float* __restrict__ out)
{
    __shared__ float ss[4][16][3][28];
    const int b   = blockIdx.x;
    const int n   = b >> 7;
    const int t0  = (b & 127) << 2;
    const int tid = threadIdx.x;
    const int o   = tid & 63;
    const int ts  = tid >> 6;

    float* sf = &ss[0][0][0][0];
    for (int e = tid; e < 4 * 16 * 3 * 28; e += 256) sf[e] = 0.f;
    __syncthreads();
    for (int e = tid; e < 4 * 16 * 75; e += 256) {
        int ts2 = e / 1200, r = e - ts2 * 1200;
        int c = r / 75, w = r - c * 75;
        int ww = w / 25, v = w - ww * 25;
        ss[ts2][c][ww][v] =
            b2f(sum12[(((size_t)n * 512 + t0 + ts2) * 16 + c) * 80 + w]);
    }
    __syncthreads();

    float wreg[48];
    #pragma unroll
    for (int k = 0; k < 48; ++k) wreg[k] = ow[o * 48 + k];
    const float scale = bg[o] * rsqrtf(bv[o] + 1e-5f);
    const float shift = bb[o] - bm[o] * scale;
    const float obv   = obias[o];

    float accs[25];
    #pragma unroll
    for (int v = 0; v < 25; ++v) accs[v] = 0.f;

    for (int c = 0; c < 16; ++c) {
        #pragma unroll
        for (int ww = 0; ww < 3; ++ww) {
            const float wv = wreg[c * 3 + ww];
            const float* sp = &ss[ts][c][ww][0];
            #pragma unroll
            for (int j = 0; j < 6; ++j) {
                float4 s4 = *(const float4*)&sp[j * 4];
                accs[j * 4 + 0] = fmaf(wv, s4.x, accs[j * 4 + 0]);
                accs[j * 4 + 1] = fmaf(wv, s4.y, accs[j * 4 + 1]);
                accs[j * 4 + 2] = fmaf(wv, s4.z, accs[j * 4 + 2]);
                accs[j * 4 + 3] = fmaf(wv, s4.w, accs[j * 4 + 3]);
            }
            accs[24] = fmaf(wv, sp[24], accs[24]);
        }
    }

    const int t = t0 + ts;
    const size_t base = (((size_t)n * 64 + o) * 512 + t) * 25;
    #pragma unroll
    for (int v = 0; v < 25; ++v) {
        float y = (accs[v] + obv) * scale + shift + x[base + v];
        out[base + v] = fmaxf(y, 0.f);
    }
}

// ---------------------------------------------------------------------------
extern "C" void kernel_launch(void* const* d_in, const int* in_sizes, int n_in,
                              void* d_out, int out_size, void* d_ws, size_t ws_size,
                              hipStream_t stream)
{
    const float* x  = (const float*)d_in[0];
    const float* A  = (const float*)d_in[1];
    const float* PA = (const float*)d_in[2];
    const float* wa = (const float*)d_in[3];
    const float* ba = (const float*)d_in[4];
    const float* wd = (const float*)d_in[5];
    const float* bd = (const float*)d_in[6];
    const float* wc = (const float*)d_in[7];
    const float* bc = (const float*)d_in[8];
    const float* ow = (const float*)d_in[9];
    const float* ob = (const float*)d_in[10];
    const float* bg = (const float*)d_in[11];
    const float* bb = (const float*)d_in[12];
    const float* bm = (const float*)d_in[13];
    const float* bv = (const float*)d_in[14];
    float* out = (float*)d_out;

    char* ws = (char*)d_ws;
    u16*   a1o   = (u16*)(ws);                           // 13,158,400 B
    u16*   hcn   = (u16*)(ws + 13158400);                // 67,108,864 B
    u16*   sum12 = (u16*)(ws + 80267264);                // 41,943,040 B
    u16*   BtA   = (u16*)(ws + 122210304);               // 46,080 B
    u16*   BtT   = (u16*)(ws + 122256384);               // 491,520 B
    float* Spart = (float*)(ws + 122747904);             // 13,107,200 B

    k0_bta    <<<90,   256, 0, stream>>>(A, PA, BtA);
    k1_conv80 <<<1024, 256, 0, stream>>>(x, wa, ba, wd, bd, wc, bc, a1o, hcn);
    k2a_mfma  <<<512,  256, 0, stream>>>(a1o, Spart);
    k2b_softmax<<<32,  256, 0, stream>>>(Spart, BtT);
    k3_graph  <<<512,  256, 0, stream>>>(hcn, BtA, BtT, sum12);
    k4_out    <<<4096, 256, 0, stream>>>(sum12, ow, ob, bg, bb, bm, bv, x, out);
}